// Round 2
// baseline (320.178 us; speedup 1.0000x reference)
//
#include <hip/hip_runtime.h>
#include <hip/hip_bf16.h>

// VectorQuantize: B=4, N=2048, DIM=256, HEADS=4, CODEBOOK=8192, HD=64
// Established (R0-R10): inputs fp32, output fp32 (quantize ++ indices-as-floats).
// R10: fp16 2-level split, 3 MFMA terms, NPART=8, 139.6us dist / 190 total.
// R11: zero-C acc init + epilogue ycn fold + setprio(1/0) around MFMA chain +
//   merge rewrite: dist 128.0us, MfmaUtil 35, VALUBusy 45.7, conflicts 0.
//   BUT total-minus-dist tail stayed ~51us => second-dispatch serialization
//   (full-grid drain + launch + merge) is the dominant residual.
// R12 (this round): FUSE merge into dist via block election.
//   Each (h,qg) group = 8 partition-blocks. All threads release-fence after
//   publishing g_pval/g_pidx; thread 0 atomicAdd's the group counter; the
//   last-arriving block acquire-fences and performs the 8-way merge + index
//   write + gather for its 256 queries. Counter self-resets (winner zeroes it)
//   so repeated launches / rocprof replays stay correct. No spin-waits.
//   Removes: merge launch, grid drain, g_pval HBM round-trip.

#define HEADS    4
#define CODEBOOK 8192
#define HD       64
#define BQ       8192                  // queries per head = B*N
#define QOFF     (4 * 2048 * 256)      // quantize FLOAT elements in d_out
#define NPART    8
#define CPART    (CODEBOOK / NPART)    // 1024 codes per partition
#define SCODES   64                    // codes per stage
#define NSTAGE   (CPART / SCODES)      // 16 stages
#define RSCALE   4096.0f               // residual scale (2^12)
#define RINV     (1.0f / 4096.0f)

typedef _Float16 f16x8 __attribute__((ext_vector_type(8)));
typedef float    f32x4 __attribute__((ext_vector_type(4)));

__device__ float g_pval[NPART][HEADS * BQ];       // per-partition best (max score)
__device__ int   g_pidx[NPART][HEADS * BQ];       // per-partition best index
__device__ int   g_cnt[HEADS * 32];               // per-(h,qg) arrival counter

// split fp32 -> 2 fp16 levels: f ~= (float)h0 + (float)h1 / 4096, |err|<=2^-24|f|
__device__ inline void split2(float f, _Float16& h0, _Float16& h1) {
    h0 = (_Float16)f;
    float r = f - (float)h0;
    h1 = (_Float16)(r * RSCALE);
}

// ---------------- fused kernel: scores + argmax + election merge ----------
// grid = 1024 = head(4) x qgroup(32) x part(8); block = 256 (4 waves).
// Each wave owns 64 queries (4 pinned A row-tiles); block scans one 1024-code
// partition in 16 stages of 64 codes through double-buffered, XOR-swizzled LDS
// (conflict-free b128 write+read — verified R5/R8: SQ_LDS_BANK_CONFLICT == 0).
// y2 (= -0.5||e||^2) computed for free inside the staging path (R8-verified).
// MFMA 16x16x32_f16 layouts (same operand shape as bf16, HW-verified family):
//   A: lane -> A[m=lane&15][k=quad*8+j];  B: lane -> B[k=quad*8+j][n=lane&15]
//   C: lane -> col=lane&15, row=quad*4+reg
__global__ __launch_bounds__(256, 2) void dist_kernel(const float* __restrict__ x,
                                                      const float* __restrict__ embed,
                                                      float* __restrict__ out) {
    __shared__ __align__(16) _Float16 tile[2][2][SCODES * 64];   // 32768 B
    __shared__ float y2s[CPART];                                 // 4096 B
    __shared__ int s_old;

    const int bid  = blockIdx.x;
    const int part = bid & 7;
    const int qg   = (bid >> 3) & 31;
    const int h    = bid >> 8;
    const int t    = threadIdx.x;
    const int wave = t >> 6;
    const int lane = t & 63;
    const int col  = lane & 15;
    const int quad = lane >> 4;

    const int qbase = qg * 256 + wave * 64;       // this wave's 64 queries
    const int cbase = part * CPART;

    // A fragments a[rowtile][level][khalf], split on the fly from fp32 x
    f16x8 a[4][2][2];
#pragma unroll
    for (int rt = 0; rt < 4; rt++) {
#pragma unroll
        for (int kh = 0; kh < 2; kh++) {
            const float* p = x + ((size_t)(qbase + rt * 16 + col) * 256 + h * 64 + kh * 32 + quad * 8);
#pragma unroll
            for (int j = 0; j < 8; j++) {
                _Float16 h0, h1;
                split2(p[j], h0, h1);
                a[rt][0][kh][j] = h0;
                a[rt][1][kh][j] = h1;
            }
        }
    }

    // staging: thread t owns rows (t>>3), (t>>3)+32, 8-float granule t&7
    const float* esrc = embed + ((size_t)h * CODEBOOK + cbase) * HD + (size_t)t * 8;
    const int row  = t >> 3;
    const int gsw  = (t & 7) ^ (row & 7);          // swizzled granule (same for row+32)
    const int ldA  = row * 64 + gsw * 8;           // f16 units within a level plane
    const int ldB  = (row + 32) * 64 + gsw * 8;

    float bv[4][4]; int bc[4][4];
#pragma unroll
    for (int rt = 0; rt < 4; rt++)
#pragma unroll
        for (int r = 0; r < 4; r++) { bv[rt][r] = -3.4e38f; bc[rt][r] = 0; }

    float4 pfA0, pfA1, pfB0, pfB1;                 // prefetch regs (2 rows x 8 floats)

    // split both rows -> 2 LDS planes of `buf`; also compute + publish -0.5*y2
    auto stage_write = [&](int buf, int stage) {
        float fA[8] = {pfA0.x, pfA0.y, pfA0.z, pfA0.w, pfA1.x, pfA1.y, pfA1.z, pfA1.w};
        float fB[8] = {pfB0.x, pfB0.y, pfB0.z, pfB0.w, pfB1.x, pfB1.y, pfB1.z, pfB1.w};
        f16x8 vA0, vA1, vB0, vB1;
        float ssA = 0.f, ssB = 0.f;
#pragma unroll
        for (int j = 0; j < 8; j++) {
            _Float16 h0, h1;
            split2(fA[j], h0, h1);
            vA0[j] = h0; vA1[j] = h1;
            ssA = fmaf(fA[j], fA[j], ssA);
            split2(fB[j], h0, h1);
            vB0[j] = h0; vB1[j] = h1;
            ssB = fmaf(fB[j], fB[j], ssB);
        }
        *reinterpret_cast<f16x8*>(&tile[buf][0][ldA]) = vA0;
        *reinterpret_cast<f16x8*>(&tile[buf][1][ldA]) = vA1;
        *reinterpret_cast<f16x8*>(&tile[buf][0][ldB]) = vB0;
        *reinterpret_cast<f16x8*>(&tile[buf][1][ldB]) = vB1;
#pragma unroll
        for (int off = 4; off >= 1; off >>= 1) {   // width-8 granule tree
            ssA += __shfl_xor(ssA, off, 8);
            ssB += __shfl_xor(ssB, off, 8);
        }
        if ((t & 7) == 0) {
            y2s[stage * SCODES + row]      = -0.5f * ssA;
            y2s[stage * SCODES + row + 32] = -0.5f * ssB;
        }
    };
    auto stage_load = [&](int stage) {
        const float* ps = esrc + (size_t)stage * (SCODES * HD);
        pfA0 = *reinterpret_cast<const float4*>(ps);
        pfA1 = *reinterpret_cast<const float4*>(ps + 4);
        pfB0 = *reinterpret_cast<const float4*>(ps + 32 * HD);
        pfB1 = *reinterpret_cast<const float4*>(ps + 32 * HD + 4);
    };

    // preamble: stage 0 staged + y2, stage 1 prefetched, publish
    stage_load(0);
    stage_write(0, 0);
    stage_load(1);
    __syncthreads();

    const int swbase = col & 7;                    // read-side swizzle key
    const f32x4 z4 = {0.f, 0.f, 0.f, 0.f};        // persistent zero C-operand

    for (int s = 0; s < NSTAGE; s++) {
        // write stage s+1 (+ its y2) into the other buffer, then issue load of
        // stage s+2; the in-flight load drains at THIS stage's end barrier.
        if (s + 1 < NSTAGE) stage_write((s + 1) & 1, s + 1);
        if (s + 2 < NSTAGE) stage_load(s + 2);

#pragma unroll
        for (int inner = 0; inner < 4; inner++) {
            const int rbase = (inner * 16 + col) * 64;     // row offset in plane
            f16x8 b[2][2];
#pragma unroll
            for (int lvl = 0; lvl < 2; lvl++)
#pragma unroll
                for (int kh = 0; kh < 2; kh++)
                    b[lvl][kh] = *reinterpret_cast<const f16x8*>(
                        &tile[s & 1][lvl][rbase + ((((kh << 2) | quad) ^ swbase) << 3)]);

            const int   c   = s * SCODES + inner * 16 + col;   // partition-local code
            const float ycn = y2s[c];                          // -0.5*||e_c||^2 (epilogue-only)
#pragma unroll
            for (int rt = 0; rt < 4; rt++) {
                __builtin_amdgcn_s_setprio(1);
                f32x4 aA = __builtin_amdgcn_mfma_f32_16x16x32_f16(a[rt][0][0], b[0][0], z4, 0, 0, 0);
                f32x4 aB = __builtin_amdgcn_mfma_f32_16x16x32_f16(a[rt][0][0], b[1][0], z4, 0, 0, 0);
                aB = __builtin_amdgcn_mfma_f32_16x16x32_f16(a[rt][1][0], b[0][0], aB, 0, 0, 0);
                aA = __builtin_amdgcn_mfma_f32_16x16x32_f16(a[rt][0][1], b[0][1], aA, 0, 0, 0);
                aB = __builtin_amdgcn_mfma_f32_16x16x32_f16(a[rt][0][1], b[1][1], aB, 0, 0, 0);
                aB = __builtin_amdgcn_mfma_f32_16x16x32_f16(a[rt][1][1], b[0][1], aB, 0, 0, 0);
                __builtin_amdgcn_s_setprio(0);
#pragma unroll
                for (int r = 0; r < 4; r++) {
                    float sv = fmaf(aB[r], RINV, aA[r] + ycn); // xy - 0.5||e||^2
                    if (sv > bv[rt][r]) { bv[rt][r] = sv; bc[rt][r] = c; }
                }
            }
        }
        __syncthreads();
    }

    // reduce across 16 column slots; lexicographic (max val, min idx) =
    // np first-argmax tie-break
#pragma unroll
    for (int rt = 0; rt < 4; rt++) {
#pragma unroll
        for (int r = 0; r < 4; r++) {
            float v = bv[rt][r]; int c = bc[rt][r];
#pragma unroll
            for (int off = 8; off >= 1; off >>= 1) {
                float ov = __shfl_xor(v, off, 16); int oc = __shfl_xor(c, off, 16);
                if (ov > v || (ov == v && oc < c)) { v = ov; c = oc; }
            }
            if (col == 0) {
                int q = h * BQ + qbase + rt * 16 + quad * 4 + r;
                g_pval[part][q] = v; g_pidx[part][q] = cbase + c;
            }
        }
    }

    // ---------------- election: last block of the (h,qg) group merges ------
    const int grp = (h << 5) | qg;
    __syncthreads();                 // all waves' g_pval/g_pidx stores issued
    __threadfence();                 // release: make them device-visible
    if (t == 0) s_old = atomicAdd(&g_cnt[grp], 1);
    __syncthreads();
    if (s_old != NPART - 1) return;  // not last -> done

    if (t == 0) atomicExch(&g_cnt[grp], 0);  // self-reset for next launch/replay
    __threadfence();                 // acquire: see other blocks' results

    // merge 8 partitions for 256 queries of head h; thread t owns query row t
    int* sidx = reinterpret_cast<int*>(y2s);     // y2s dead; reuse as idx park
    const int m0 = qg * 256;
    {
        const int q = h * BQ + m0 + t;
        float mv = g_pval[0][q]; int mc = g_pidx[0][q];
#pragma unroll
        for (int p = 1; p < NPART; p++) {
            float v = g_pval[p][q]; int c = g_pidx[p][q];
            if (v > mv || (v == mv && c < mc)) { mv = v; mc = c; }
        }
        out[QOFF + (size_t)(m0 + t) * 4 + h] = (float)mc;   // embed_ind[b][n][h]
        sidx[t] = mc & (CODEBOOK - 1);                      // defensive in-range
    }
    __syncthreads();

    // gather: wave owns 64 rows; 16 lanes per row x 4 rows per iter -> fully
    // coalesced 256B reads per codebook row and 256B stores per output row.
    const int rr = lane >> 4;                    // row-in-quad 0..3
    const int fo = (lane & 15) * 4;              // float offset within head seg
#pragma unroll
    for (int i = 0; i < 16; i++) {
        const int r   = wave * 64 + i * 4 + rr;
        const int idx = sidx[r];
        const float4 v = *reinterpret_cast<const float4*>(
            embed + ((size_t)h * CODEBOOK + idx) * HD + fo);
        *reinterpret_cast<float4*>(out + (size_t)(m0 + r) * 256 + h * 64 + fo) = v;
    }
}

extern "C" void kernel_launch(void* const* d_in, const int* in_sizes, int n_in,
                              void* d_out, int out_size, void* d_ws, size_t ws_size,
                              hipStream_t stream) {
    const float* x     = (const float*)d_in[0];
    const float* embed = (const float*)d_in[1];
    float*       out   = (float*)d_out;

    dist_kernel<<<1024, 256, 0, stream>>>(x, embed, out);
}

// Round 3
// 176.236 us; speedup vs baseline: 1.8168x; 1.8168x over previous
//
#include <hip/hip_runtime.h>
#include <hip/hip_bf16.h>

// VectorQuantize: B=4, N=2048, DIM=256, HEADS=4, CODEBOOK=8192, HD=64
// Established (R0-R10): inputs fp32, output fp32 (quantize ++ indices-as-floats).
// R10: fp16 2-level split, 3 MFMA terms, NPART=8, 139.6us dist / 190 total.
// R11: zero-C acc init + epilogue ycn fold + setprio + merge rewrite:
//   dist 128.0us, MfmaUtil 35, total 178.8us (tail ~51us).
// R12: election fusion w/ __threadfence(): DISASTER (296us steady dist).
//   __threadfence = buffer_wbl2 L2-writeback x1024 blocks -> cache thrash.
//   Useful fact: single-kernel harness overhead ~24us (vs ~51 for 2 kernels).
// R13 (this round): fence-FREE fusion via device-scope atomics.
//   - per-query packed 64b atomicMax(g_best): hi32 = sortable(score),
//     lo32 = ~idx  => max == (max score, min idx) == np first-argmax.
//     Cross-partition merge happens inside the atomic; no 8-way reader.
//   - release ordering free: __syncthreads() drains vmcnt(0) before the
//     election atomicAdd; atomics execute at the coherent point (m20:
//     global atomics are device-scope). NO __threadfence anywhere.
//   - winner (8th arrival of (h,qg)) reads finals via atomicAdd(p,0),
//     writes indices + gathers. Counter self-resets; atomicMax idempotent
//     across launches/replays (deterministic scores), init 0 never wins.

#define HEADS    4
#define CODEBOOK 8192
#define HD       64
#define BQ       8192                  // queries per head = B*N
#define QOFF     (4 * 2048 * 256)      // quantize FLOAT elements in d_out
#define NPART    8
#define CPART    (CODEBOOK / NPART)    // 1024 codes per partition
#define SCODES   64                    // codes per stage
#define NSTAGE   (CPART / SCODES)      // 16 stages
#define RSCALE   4096.0f               // residual scale (2^12)
#define RINV     (1.0f / 4096.0f)

typedef _Float16 f16x8 __attribute__((ext_vector_type(8)));
typedef float    f32x4 __attribute__((ext_vector_type(4)));

__device__ unsigned long long g_best[HEADS * BQ]; // packed (sortable score, ~idx)
__device__ int                g_cnt[HEADS * 32];  // per-(h,qg) arrival counter

// split fp32 -> 2 fp16 levels: f ~= (float)h0 + (float)h1 / 4096, |err|<=2^-24|f|
__device__ inline void split2(float f, _Float16& h0, _Float16& h1) {
    h0 = (_Float16)f;
    float r = f - (float)h0;
    h1 = (_Float16)(r * RSCALE);
}

// order-preserving float->uint32 (finite values; scores are finite)
__device__ inline unsigned sortable(float v) {
    unsigned s = __float_as_uint(v);
    return s ^ ((s & 0x80000000u) ? 0xFFFFFFFFu : 0x80000000u);
}

// ---------------- fused kernel: scores + argmax + election merge ----------
// grid = 1024 = head(4) x qgroup(32) x part(8); block = 256 (4 waves).
// Each wave owns 64 queries (4 pinned A row-tiles); block scans one 1024-code
// partition in 16 stages of 64 codes through double-buffered, XOR-swizzled LDS
// (conflict-free b128 write+read — verified R5/R8: SQ_LDS_BANK_CONFLICT == 0).
// y2 (= -0.5||e||^2) computed for free inside the staging path (R8-verified).
// MFMA 16x16x32_f16 layouts (same operand shape as bf16, HW-verified family):
//   A: lane -> A[m=lane&15][k=quad*8+j];  B: lane -> B[k=quad*8+j][n=lane&15]
//   C: lane -> col=lane&15, row=quad*4+reg
__global__ __launch_bounds__(256, 2) void dist_kernel(const float* __restrict__ x,
                                                      const float* __restrict__ embed,
                                                      float* __restrict__ out) {
    __shared__ __align__(16) _Float16 tile[2][2][SCODES * 64];   // 32768 B
    __shared__ float y2s[CPART];                                 // 4096 B
    __shared__ int s_old;

    const int bid  = blockIdx.x;
    const int part = bid & 7;
    const int qg   = (bid >> 3) & 31;
    const int h    = bid >> 8;
    const int t    = threadIdx.x;
    const int wave = t >> 6;
    const int lane = t & 63;
    const int col  = lane & 15;
    const int quad = lane >> 4;

    const int qbase = qg * 256 + wave * 64;       // this wave's 64 queries
    const int cbase = part * CPART;

    // A fragments a[rowtile][level][khalf], split on the fly from fp32 x
    f16x8 a[4][2][2];
#pragma unroll
    for (int rt = 0; rt < 4; rt++) {
#pragma unroll
        for (int kh = 0; kh < 2; kh++) {
            const float* p = x + ((size_t)(qbase + rt * 16 + col) * 256 + h * 64 + kh * 32 + quad * 8);
#pragma unroll
            for (int j = 0; j < 8; j++) {
                _Float16 h0, h1;
                split2(p[j], h0, h1);
                a[rt][0][kh][j] = h0;
                a[rt][1][kh][j] = h1;
            }
        }
    }

    // staging: thread t owns rows (t>>3), (t>>3)+32, 8-float granule t&7
    const float* esrc = embed + ((size_t)h * CODEBOOK + cbase) * HD + (size_t)t * 8;
    const int row  = t >> 3;
    const int gsw  = (t & 7) ^ (row & 7);          // swizzled granule (same for row+32)
    const int ldA  = row * 64 + gsw * 8;           // f16 units within a level plane
    const int ldB  = (row + 32) * 64 + gsw * 8;

    float bv[4][4]; int bc[4][4];
#pragma unroll
    for (int rt = 0; rt < 4; rt++)
#pragma unroll
        for (int r = 0; r < 4; r++) { bv[rt][r] = -3.4e38f; bc[rt][r] = 0; }

    float4 pfA0, pfA1, pfB0, pfB1;                 // prefetch regs (2 rows x 8 floats)

    // split both rows -> 2 LDS planes of `buf`; also compute + publish -0.5*y2
    auto stage_write = [&](int buf, int stage) {
        float fA[8] = {pfA0.x, pfA0.y, pfA0.z, pfA0.w, pfA1.x, pfA1.y, pfA1.z, pfA1.w};
        float fB[8] = {pfB0.x, pfB0.y, pfB0.z, pfB0.w, pfB1.x, pfB1.y, pfB1.z, pfB1.w};
        f16x8 vA0, vA1, vB0, vB1;
        float ssA = 0.f, ssB = 0.f;
#pragma unroll
        for (int j = 0; j < 8; j++) {
            _Float16 h0, h1;
            split2(fA[j], h0, h1);
            vA0[j] = h0; vA1[j] = h1;
            ssA = fmaf(fA[j], fA[j], ssA);
            split2(fB[j], h0, h1);
            vB0[j] = h0; vB1[j] = h1;
            ssB = fmaf(fB[j], fB[j], ssB);
        }
        *reinterpret_cast<f16x8*>(&tile[buf][0][ldA]) = vA0;
        *reinterpret_cast<f16x8*>(&tile[buf][1][ldA]) = vA1;
        *reinterpret_cast<f16x8*>(&tile[buf][0][ldB]) = vB0;
        *reinterpret_cast<f16x8*>(&tile[buf][1][ldB]) = vB1;
#pragma unroll
        for (int off = 4; off >= 1; off >>= 1) {   // width-8 granule tree
            ssA += __shfl_xor(ssA, off, 8);
            ssB += __shfl_xor(ssB, off, 8);
        }
        if ((t & 7) == 0) {
            y2s[stage * SCODES + row]      = -0.5f * ssA;
            y2s[stage * SCODES + row + 32] = -0.5f * ssB;
        }
    };
    auto stage_load = [&](int stage) {
        const float* ps = esrc + (size_t)stage * (SCODES * HD);
        pfA0 = *reinterpret_cast<const float4*>(ps);
        pfA1 = *reinterpret_cast<const float4*>(ps + 4);
        pfB0 = *reinterpret_cast<const float4*>(ps + 32 * HD);
        pfB1 = *reinterpret_cast<const float4*>(ps + 32 * HD + 4);
    };

    // preamble: stage 0 staged + y2, stage 1 prefetched, publish
    stage_load(0);
    stage_write(0, 0);
    stage_load(1);
    __syncthreads();

    const int swbase = col & 7;                    // read-side swizzle key
    const f32x4 z4 = {0.f, 0.f, 0.f, 0.f};        // persistent zero C-operand

    for (int s = 0; s < NSTAGE; s++) {
        // write stage s+1 (+ its y2) into the other buffer, then issue load of
        // stage s+2; the in-flight load drains at THIS stage's end barrier.
        if (s + 1 < NSTAGE) stage_write((s + 1) & 1, s + 1);
        if (s + 2 < NSTAGE) stage_load(s + 2);

#pragma unroll
        for (int inner = 0; inner < 4; inner++) {
            const int rbase = (inner * 16 + col) * 64;     // row offset in plane
            f16x8 b[2][2];
#pragma unroll
            for (int lvl = 0; lvl < 2; lvl++)
#pragma unroll
                for (int kh = 0; kh < 2; kh++)
                    b[lvl][kh] = *reinterpret_cast<const f16x8*>(
                        &tile[s & 1][lvl][rbase + ((((kh << 2) | quad) ^ swbase) << 3)]);

            const int   c   = s * SCODES + inner * 16 + col;   // partition-local code
            const float ycn = y2s[c];                          // -0.5*||e_c||^2 (epilogue-only)
#pragma unroll
            for (int rt = 0; rt < 4; rt++) {
                __builtin_amdgcn_s_setprio(1);
                f32x4 aA = __builtin_amdgcn_mfma_f32_16x16x32_f16(a[rt][0][0], b[0][0], z4, 0, 0, 0);
                f32x4 aB = __builtin_amdgcn_mfma_f32_16x16x32_f16(a[rt][0][0], b[1][0], z4, 0, 0, 0);
                aB = __builtin_amdgcn_mfma_f32_16x16x32_f16(a[rt][1][0], b[0][0], aB, 0, 0, 0);
                aA = __builtin_amdgcn_mfma_f32_16x16x32_f16(a[rt][0][1], b[0][1], aA, 0, 0, 0);
                aB = __builtin_amdgcn_mfma_f32_16x16x32_f16(a[rt][0][1], b[1][1], aB, 0, 0, 0);
                aB = __builtin_amdgcn_mfma_f32_16x16x32_f16(a[rt][1][1], b[0][1], aB, 0, 0, 0);
                __builtin_amdgcn_s_setprio(0);
#pragma unroll
                for (int r = 0; r < 4; r++) {
                    float sv = fmaf(aB[r], RINV, aA[r] + ycn); // xy - 0.5||e||^2
                    if (sv > bv[rt][r]) { bv[rt][r] = sv; bc[rt][r] = c; }
                }
            }
        }
        __syncthreads();
    }

    // reduce across 16 column slots; lexicographic (max val, min idx) =
    // np first-argmax tie-break; publish via packed device-scope atomicMax
#pragma unroll
    for (int rt = 0; rt < 4; rt++) {
#pragma unroll
        for (int r = 0; r < 4; r++) {
            float v = bv[rt][r]; int c = bc[rt][r];
#pragma unroll
            for (int off = 8; off >= 1; off >>= 1) {
                float ov = __shfl_xor(v, off, 16); int oc = __shfl_xor(c, off, 16);
                if (ov > v || (ov == v && oc < c)) { v = ov; c = oc; }
            }
            if (col == 0) {
                int q = h * BQ + qbase + rt * 16 + quad * 4 + r;
                unsigned long long pk =
                    ((unsigned long long)sortable(v) << 32) | (unsigned)(~(cbase + c));
                atomicMax(&g_best[q], pk);
            }
        }
    }

    // ---------------- election: last block of the (h,qg) group finalizes ---
    // __syncthreads drains vmcnt(0) => this block's atomicMaxes complete at
    // the coherent point before t0's counter add. No threadfence (R12 lesson).
    const int grp = (h << 5) | qg;
    __syncthreads();
    if (t == 0) s_old = atomicAdd(&g_cnt[grp], 1);
    __syncthreads();
    if (s_old != NPART - 1) return;  // not last -> done

    if (t == 0) atomicExch(&g_cnt[grp], 0);  // self-reset for next launch/replay

    // finalize 256 queries of (h,qg): coherent read via atomic RMW (add 0)
    int* sidx = reinterpret_cast<int*>(y2s);     // y2s dead; reuse as idx park
    const int m0 = qg * 256;
    {
        const int q = h * BQ + m0 + t;
        unsigned long long pk = atomicAdd(&g_best[q], 0ull);
        int mc = (int)(~(unsigned)pk) & (CODEBOOK - 1);
        out[QOFF + (size_t)(m0 + t) * 4 + h] = (float)mc;   // embed_ind[b][n][h]
        sidx[t] = mc;
    }
    __syncthreads();

    // gather: wave owns 64 rows; 16 lanes per row x 4 rows per iter -> fully
    // coalesced 256B reads per codebook row and 256B stores per output row.
    const int rr = lane >> 4;                    // row-in-quad 0..3
    const int fo = (lane & 15) * 4;              // float offset within head seg
#pragma unroll
    for (int i = 0; i < 16; i++) {
        const int r   = wave * 64 + i * 4 + rr;
        const int idx = sidx[r];
        const float4 v = *reinterpret_cast<const float4*>(
            embed + ((size_t)h * CODEBOOK + idx) * HD + fo);
        *reinterpret_cast<float4*>(out + (size_t)(m0 + r) * 256 + h * 64 + fo) = v;
    }
}

extern "C" void kernel_launch(void* const* d_in, const int* in_sizes, int n_in,
                              void* d_out, int out_size, void* d_ws, size_t ws_size,
                              hipStream_t stream) {
    const float* x     = (const float*)d_in[0];
    const float* embed = (const float*)d_in[1];
    float*       out   = (float*)d_out;

    dist_kernel<<<1024, 256, 0, stream>>>(x, embed, out);
}